// Round 5
// baseline (91.374 us; speedup 1.0000x reference)
//
#include <hip/hip_runtime.h>

// Problem constants (from reference setup_inputs)
#define QDIM 900
#define CDIM 80
#define TDIM 300
#define QPB 36               // q's per block (4 waves x 9)
#define QPW 9                // q's per wave
#define NQB (QDIM / QPB)     // 25 blocks per batch

typedef float floatx4 __attribute__((ext_vector_type(4)));  // native vector for NT store

struct TgtReg {
    float x0, y0, x1, y1;    // xyxy
    float cx, cy, w, h;      // cxcywh
    float area;
    int   lab;
};

__device__ __forceinline__ float cost_one(
    float ax0, float ay0, float ax1, float ay1,
    float acx, float acy, float aw, float ah, float area_a,
    const float* __restrict__ clsrow, const TgtReg& t)
{
    float clsv = clsrow[t.lab];

    // intersection
    float ix0 = fmaxf(ax0, t.x0), iy0 = fmaxf(ay0, t.y0);
    float ix1 = fminf(ax1, t.x1), iy1 = fminf(ay1, t.y1);
    float iw = fmaxf(ix1 - ix0, 0.0f), ih = fmaxf(iy1 - iy0, 0.0f);
    float inter = iw * ih;
    float uni = (area_a + t.area) - inter;

    // enclosing box
    float cx0 = fminf(ax0, t.x0), cy0 = fminf(ay0, t.y0);
    float cx1 = fmaxf(ax1, t.x1), cy1 = fmaxf(ay1, t.y1);
    float areac = (cx1 - cx0) * (cy1 - cy0);

    // L1 in cxcywh
    float l1 = fabsf(acx - t.cx) + fabsf(acy - t.cy)
             + fabsf(aw - t.w)   + fabsf(ah - t.h);

    // cost = (2 - 2*sig) + 5*l1 - 2*(inter/uni + uni/areac)
    float r = inter * __builtin_amdgcn_rcpf(uni);
    r = fmaf(uni, __builtin_amdgcn_rcpf(areac), r);
    float acc = fmaf(5.0f, l1, clsv);
    return fmaf(-2.0f, r, acc);
}

__device__ __forceinline__ TgtReg load_tgt(const float4* tb4, const int* lb, int t)
{
    TgtReg r;
    float4 v = tb4[t];
    r.cx = v.x; r.cy = v.y; r.w = v.z; r.h = v.w;
    float hw = 0.5f * v.z, hh = 0.5f * v.w;
    r.x0 = v.x - hw; r.y0 = v.y - hh;
    r.x1 = v.x + hw; r.y1 = v.y + hh;
    r.area = v.z * v.w;
    r.lab = lb[t];
    return r;
}

__global__ __launch_bounds__(256) void matcher_cost_kernel(
    const float* __restrict__ pred_logits,  // [B,Q,C]
    const float* __restrict__ pred_boxes,   // [B,Q,4] cxcywh
    const int*   __restrict__ tgt_labels,   // [B,T]
    const float* __restrict__ tgt_boxes,    // [B,T,4] cxcywh
    float* __restrict__ out)                // [B,Q,T]
{
    // s_cls[ql*C + c] = 2 - 2*sigmoid(logit) = 2/(1+e^x)
    // (the +2 comes from folding giou = iou - 1 + uni/areac)
    __shared__ float s_cls[QPB * CDIM];     // 11.25 KB

    const int tid = threadIdx.x;
    const int b  = blockIdx.x / NQB;
    const int q0 = (blockIdx.x % NQB) * QPB;

    const float* lg = pred_logits + ((size_t)b * QDIM + q0) * CDIM;
    for (int i = tid; i < QPB * CDIM; i += 256) {
        float x = lg[i];
        s_cls[i] = 2.0f * __builtin_amdgcn_rcpf(1.0f + __expf(x));
    }
    __syncthreads();

    const int wave = tid >> 6;
    const int lane = tid & 63;

    // ---- target data in registers ----
    // slice A: lane owns t = 4*lane .. 4*lane+3  (t < 256)  -> float4 NT store
    // slice B: lane owns t = 256+lane (lane < 44)           -> scalar NT store
    const float4* tb4 = reinterpret_cast<const float4*>(tgt_boxes) + (size_t)b * TDIM;
    const int*    lb  = tgt_labels + (size_t)b * TDIM;

    TgtReg A[4];
    #pragma unroll
    for (int i = 0; i < 4; ++i) A[i] = load_tgt(tb4, lb, 4 * lane + i);

    const bool bok = lane < (TDIM - 256);            // lane < 44
    const int  tB  = bok ? (256 + lane) : (TDIM - 1);
    TgtReg Bt = load_tgt(tb4, lb, tB);

    // ---- q loop: wave owns 9 contiguous q's ----
    const int qw = q0 + wave * QPW;
    const float4* pb4 = reinterpret_cast<const float4*>(pred_boxes) + (size_t)b * QDIM + qw;
    float* orow0 = out + ((size_t)b * QDIM + qw) * TDIM;

    #pragma unroll 1
    for (int j = 0; j < QPW; ++j) {
        float4 a = pb4[j];
        const float hw = 0.5f * a.z, hh = 0.5f * a.w;
        const float ax0 = a.x - hw, ay0 = a.y - hh;
        const float ax1 = a.x + hw, ay1 = a.y + hh;
        const float area_a = a.z * a.w;
        const float* clsrow = s_cls + (wave * QPW + j) * CDIM;
        float* po = orow0 + j * TDIM;

        floatx4 res;
        res.x = cost_one(ax0, ay0, ax1, ay1, a.x, a.y, a.z, a.w, area_a, clsrow, A[0]);
        res.y = cost_one(ax0, ay0, ax1, ay1, a.x, a.y, a.z, a.w, area_a, clsrow, A[1]);
        res.z = cost_one(ax0, ay0, ax1, ay1, a.x, a.y, a.z, a.w, area_a, clsrow, A[2]);
        res.w = cost_one(ax0, ay0, ax1, ay1, a.x, a.y, a.z, a.w, area_a, clsrow, A[3]);
        __builtin_nontemporal_store(res, reinterpret_cast<floatx4*>(po) + lane);

        float cB = cost_one(ax0, ay0, ax1, ay1, a.x, a.y, a.z, a.w, area_a, clsrow, Bt);
        if (bok)
            __builtin_nontemporal_store(cB, po + 256 + lane);
    }
}

extern "C" void kernel_launch(void* const* d_in, const int* in_sizes, int n_in,
                              void* d_out, int out_size, void* d_ws, size_t ws_size,
                              hipStream_t stream) {
    const float* pred_logits = (const float*)d_in[0];
    const float* pred_boxes  = (const float*)d_in[1];
    const int*   tgt_labels  = (const int*)d_in[2];
    const float* tgt_boxes   = (const float*)d_in[3];
    float* out = (float*)d_out;

    const int B = in_sizes[0] / (QDIM * CDIM);   // 256
    dim3 grid(B * NQB);                          // 256 * 25 = 6400
    dim3 block(256);
    matcher_cost_kernel<<<grid, block, 0, stream>>>(pred_logits, pred_boxes,
                                                    tgt_labels, tgt_boxes, out);
}

// Round 6
// 86.988 us; speedup vs baseline: 1.0504x; 1.0504x over previous
//
#include <hip/hip_runtime.h>

// Problem constants (from reference setup_inputs)
#define QDIM 900
#define CDIM 80
#define TDIM 300
#define QPB 36               // q's per block (4 waves x 9)
#define QPW 9                // q's per wave
#define NQB (QDIM / QPB)     // 25 blocks per batch

typedef float floatx4 __attribute__((ext_vector_type(4)));  // native vector for NT store

struct TgtReg {
    float x0, y0, x1, y1;    // xyxy
    float cx, cy, w, h;      // cxcywh
    float area;
    int   lab;
};

__device__ __forceinline__ float cost_one(
    float ax0, float ay0, float ax1, float ay1,
    float acx, float acy, float aw, float ah, float area_a,
    const float* __restrict__ clsrow, const TgtReg& t)
{
    float clsv = clsrow[t.lab];

    // intersection (raw, unclamped) + enclosing via identity:
    //   cw = aw + bw - iw_raw,  ch = ah + bh - ih_raw
    float M0x = fmaxf(ax0, t.x0);
    float m1x = fminf(ax1, t.x1);
    float iwr = m1x - M0x;
    float iw  = fmaxf(iwr, 0.0f);
    float cw  = (aw + t.w) - iwr;

    float M0y = fmaxf(ay0, t.y0);
    float m1y = fminf(ay1, t.y1);
    float ihr = m1y - M0y;
    float ih  = fmaxf(ihr, 0.0f);
    float ch  = (ah + t.h) - ihr;

    float inter = iw * ih;
    float areac = cw * ch;
    float uni   = (area_a + t.area) - inter;

    // inter/uni + uni/areac = (inter*areac + uni^2) / (uni*areac)  -- one rcp
    float num   = fmaf(uni, uni, inter * areac);
    float den   = uni * areac;
    float ratio = num * __builtin_amdgcn_rcpf(den);

    // L1 in cxcywh
    float l1 = fabsf(acx - t.cx) + fabsf(acy - t.cy)
             + fabsf(aw - t.w)   + fabsf(ah - t.h);

    // cost = (2 - 2*sig) + 5*l1 - 2*(inter/uni + uni/areac)
    float acc = fmaf(5.0f, l1, clsv);
    return fmaf(-2.0f, ratio, acc);
}

__device__ __forceinline__ TgtReg load_tgt(const float4* tb4, const int* lb, int t)
{
    TgtReg r;
    float4 v = tb4[t];
    r.cx = v.x; r.cy = v.y; r.w = v.z; r.h = v.w;
    float hw = 0.5f * v.z, hh = 0.5f * v.w;
    r.x0 = v.x - hw; r.y0 = v.y - hh;
    r.x1 = v.x + hw; r.y1 = v.y + hh;
    r.area = v.z * v.w;
    r.lab = lb[t];
    return r;
}

__global__ __launch_bounds__(256, 4) void matcher_cost_kernel(
    const float* __restrict__ pred_logits,  // [B,Q,C]
    const float* __restrict__ pred_boxes,   // [B,Q,4] cxcywh
    const int*   __restrict__ tgt_labels,   // [B,T]
    const float* __restrict__ tgt_boxes,    // [B,T,4] cxcywh
    float* __restrict__ out)                // [B,Q,T]
{
    // s_cls[ql*C + c] = 2 - 2*sigmoid(logit) = 2/(1+e^x)
    // (the +2 comes from folding giou = iou - 1 + uni/areac)
    __shared__ float s_cls[QPB * CDIM];     // 11.25 KB

    const int tid = threadIdx.x;
    const int b  = blockIdx.x / NQB;
    const int q0 = (blockIdx.x % NQB) * QPB;

    const float* lg = pred_logits + ((size_t)b * QDIM + q0) * CDIM;
    for (int i = tid; i < QPB * CDIM; i += 256) {
        float x = lg[i];
        s_cls[i] = 2.0f * __builtin_amdgcn_rcpf(1.0f + __expf(x));
    }
    __syncthreads();

    const int wave = tid >> 6;
    const int lane = tid & 63;

    // ---- target data in registers ----
    // slice A: lane owns t = 4*lane .. 4*lane+3  (t < 256)  -> float4 NT store
    // slice B: lane owns t = 256+lane (lane < 44)           -> scalar NT store
    const float4* tb4 = reinterpret_cast<const float4*>(tgt_boxes) + (size_t)b * TDIM;
    const int*    lb  = tgt_labels + (size_t)b * TDIM;

    TgtReg A[4];
    #pragma unroll
    for (int i = 0; i < 4; ++i) A[i] = load_tgt(tb4, lb, 4 * lane + i);

    const bool bok = lane < (TDIM - 256);            // lane < 44
    const int  tB  = bok ? (256 + lane) : (TDIM - 1);
    TgtReg Bt = load_tgt(tb4, lb, tB);

    // ---- q loop: wave owns 9 contiguous q's ----
    const int qw = q0 + wave * QPW;
    const float4* pb4 = reinterpret_cast<const float4*>(pred_boxes) + (size_t)b * QDIM + qw;
    float* orow0 = out + ((size_t)b * QDIM + qw) * TDIM;

    #pragma unroll 1
    for (int j = 0; j < QPW; ++j) {
        float4 a = pb4[j];
        const float hw = 0.5f * a.z, hh = 0.5f * a.w;
        const float ax0 = a.x - hw, ay0 = a.y - hh;
        const float ax1 = a.x + hw, ay1 = a.y + hh;
        const float area_a = a.z * a.w;
        const float* clsrow = s_cls + (wave * QPW + j) * CDIM;
        float* po = orow0 + j * TDIM;

        floatx4 res;
        res.x = cost_one(ax0, ay0, ax1, ay1, a.x, a.y, a.z, a.w, area_a, clsrow, A[0]);
        res.y = cost_one(ax0, ay0, ax1, ay1, a.x, a.y, a.z, a.w, area_a, clsrow, A[1]);
        res.z = cost_one(ax0, ay0, ax1, ay1, a.x, a.y, a.z, a.w, area_a, clsrow, A[2]);
        res.w = cost_one(ax0, ay0, ax1, ay1, a.x, a.y, a.z, a.w, area_a, clsrow, A[3]);
        __builtin_nontemporal_store(res, reinterpret_cast<floatx4*>(po) + lane);

        float cB = cost_one(ax0, ay0, ax1, ay1, a.x, a.y, a.z, a.w, area_a, clsrow, Bt);
        if (bok)
            __builtin_nontemporal_store(cB, po + 256 + lane);
    }
}

extern "C" void kernel_launch(void* const* d_in, const int* in_sizes, int n_in,
                              void* d_out, int out_size, void* d_ws, size_t ws_size,
                              hipStream_t stream) {
    const float* pred_logits = (const float*)d_in[0];
    const float* pred_boxes  = (const float*)d_in[1];
    const int*   tgt_labels  = (const int*)d_in[2];
    const float* tgt_boxes   = (const float*)d_in[3];
    float* out = (float*)d_out;

    const int B = in_sizes[0] / (QDIM * CDIM);   // 256
    dim3 grid(B * NQB);                          // 256 * 25 = 6400
    dim3 block(256);
    matcher_cost_kernel<<<grid, block, 0, stream>>>(pred_logits, pred_boxes,
                                                    tgt_labels, tgt_boxes, out);
}